// Round 7
// baseline (655.809 us; speedup 1.0000x reference)
//
#include <hip/hip_runtime.h>
#include <math.h>

#define NB 8
#define NREG 64
#define DIM 1024
#define ADIM 128
#define CHUNKS 128               // row chunks in segsum (grid = CHUNKS*4)

typedef float f4 __attribute__((ext_vector_type(4)));

// ---------------- ws layout (bytes) ----------------
// sums    f32[64*1024]  @ 0        (262144)
// counts  u32[64]       @ 262144   (256)
// scores  f32[64]       @ 262400   (256)
// partial f4[64]        @ 262656   (1024)  per-block minmax {mnx,mny,mxx,mxy}
// rid     u8[N pad]     @ 263680   (~100 KB)
#define SUMS_OFF  0
#define CNT_OFF   262144
#define SCORE_OFF 262400
#define PART_OFF  262656
#define RID_OFF   263680

// K1: per-block coords minmax partials + zero accumulators + seed logit. grid 64.
__global__ __launch_bounds__(256) void k_minmax_init(const float2* __restrict__ coords,
                                                     int N,
                                                     float4* __restrict__ partial,
                                                     float* __restrict__ sums,
                                                     unsigned* __restrict__ counts,
                                                     float* __restrict__ scores,
                                                     float* __restrict__ out,
                                                     const float* __restrict__ c2_b) {
    int b = blockIdx.x, t = threadIdx.x;
    ((float4*)sums)[b * 256 + t] = make_float4(0.f, 0.f, 0.f, 0.f);
    if (b == 0) {
        if (t < NREG) { counts[t] = 0u; scores[t] = 0.f; }
        else if (t == 64) out[0] = c2_b[0];
    }
    float mnx = 1e30f, mny = 1e30f, mxx = -1e30f, mxy = -1e30f;
    for (int i = b * 256 + t; i < N; i += 64 * 256) {
        float2 c = coords[i];
        mnx = fminf(mnx, c.x); mny = fminf(mny, c.y);
        mxx = fmaxf(mxx, c.x); mxy = fmaxf(mxy, c.y);
    }
    for (int off = 32; off; off >>= 1) {
        mnx = fminf(mnx, __shfl_xor(mnx, off));
        mny = fminf(mny, __shfl_xor(mny, off));
        mxx = fmaxf(mxx, __shfl_xor(mxx, off));
        mxy = fmaxf(mxy, __shfl_xor(mxy, off));
    }
    __shared__ float s[4][4];
    int w = t >> 6, lane = t & 63;
    if (lane == 0) { s[w][0] = mnx; s[w][1] = mny; s[w][2] = mxx; s[w][3] = mxy; }
    __syncthreads();
    if (t == 0) {
        for (int i = 1; i < 4; ++i) {
            s[0][0] = fminf(s[0][0], s[i][0]);
            s[0][1] = fminf(s[0][1], s[i][1]);
            s[0][2] = fmaxf(s[0][2], s[i][2]);
            s[0][3] = fmaxf(s[0][3], s[i][3]);
        }
        partial[b] = make_float4(s[0][0], s[0][1], s[0][2], s[0][3]);
    }
}

// K2: reduce minmax partials in-block; write rid[i] (u8) + counts histogram.
__global__ __launch_bounds__(256) void k_rid(const float2* __restrict__ coords, int N,
                                             const float4* __restrict__ partial,
                                             unsigned char* __restrict__ rid,
                                             unsigned* __restrict__ counts) {
    __shared__ float prm[4];          // lox, loy, spx, spy
    __shared__ unsigned lcnt[NREG];
    int t = threadIdx.x;
    if (t < NREG) lcnt[t] = 0u;
    if (t < 64) {
        float4 p = partial[t];
        float mnx = p.x, mny = p.y, mxx = p.z, mxy = p.w;
        for (int off = 32; off; off >>= 1) {
            mnx = fminf(mnx, __shfl_xor(mnx, off));
            mny = fminf(mny, __shfl_xor(mny, off));
            mxx = fmaxf(mxx, __shfl_xor(mxx, off));
            mxy = fmaxf(mxy, __shfl_xor(mxy, off));
        }
        if (t == 0) {
            prm[0] = mnx; prm[1] = mny;
            prm[2] = fmaxf(mxx - mnx, 1.0f);
            prm[3] = fmaxf(mxy - mny, 1.0f);
        }
    }
    __syncthreads();
    int i = blockIdx.x * 256 + t;
    if (i < N) {
        float2 c = coords[i];
        float qx = ((c.x - prm[0]) / prm[2]) * (float)NB;
        float qy = ((c.y - prm[1]) / prm[3]) * (float)NB;
        int bx = min(max((int)qx, 0), NB - 1);
        int by = min(max((int)qy, 0), NB - 1);
        int r = by * NB + bx;
        rid[i] = (unsigned char)r;
        atomicAdd(&lcnt[r], 1u);
    }
    __syncthreads();
    if (t < NREG && lcnt[t]) atomicAdd(&counts[t], lcnt[t]);
}

// K3: sequential-order segment sum. Block = (row chunk, col quarter).
// Wave owns a row; lane t covers cols q*256 + t + 64k. LDS [64][256] f32,
// ds_add conflict-free (bank = t%32, rid uniform per row).
__global__ __launch_bounds__(256) void k_segsum(const float* __restrict__ x,
                                                const unsigned char* __restrict__ rid,
                                                int N, int rpc,
                                                float* __restrict__ sums) {
    __shared__ float lsum[NREG * 256];   // 64 KB
    int t = threadIdx.x;
    int q = blockIdx.x & 3;
    int c = blockIdx.x >> 2;
    #pragma unroll
    for (int i = 0; i < NREG; ++i) lsum[i * 256 + t] = 0.f;
    __syncthreads();

    int w = t >> 6, lane = t & 63;
    int row_lo = c * rpc;                 // rpc multiple of 32 -> 8-aligned groups
    int row_hi = min(N, row_lo + rpc);
    const float* xq = x + q * 256 + lane;

    for (int row0 = row_lo + w * 8; row0 + 8 <= row_hi; row0 += 32) {
        uint2 rr = *(const uint2*)(rid + row0);
        float v0[4], v1[4], v2[4], v3[4], v4[4], v5[4], v6[4], v7[4];
        const float* p;
        p = xq + (size_t)(row0 + 0) * DIM; v0[0]=p[0]; v0[1]=p[64]; v0[2]=p[128]; v0[3]=p[192];
        p = xq + (size_t)(row0 + 1) * DIM; v1[0]=p[0]; v1[1]=p[64]; v1[2]=p[128]; v1[3]=p[192];
        p = xq + (size_t)(row0 + 2) * DIM; v2[0]=p[0]; v2[1]=p[64]; v2[2]=p[128]; v2[3]=p[192];
        p = xq + (size_t)(row0 + 3) * DIM; v3[0]=p[0]; v3[1]=p[64]; v3[2]=p[128]; v3[3]=p[192];
        p = xq + (size_t)(row0 + 4) * DIM; v4[0]=p[0]; v4[1]=p[64]; v4[2]=p[128]; v4[3]=p[192];
        p = xq + (size_t)(row0 + 5) * DIM; v5[0]=p[0]; v5[1]=p[64]; v5[2]=p[128]; v5[3]=p[192];
        p = xq + (size_t)(row0 + 6) * DIM; v6[0]=p[0]; v6[1]=p[64]; v6[2]=p[128]; v6[3]=p[192];
        p = xq + (size_t)(row0 + 7) * DIM; v7[0]=p[0]; v7[1]=p[64]; v7[2]=p[128]; v7[3]=p[192];
        float* d;
        d = lsum + ((rr.x       ) & 63u) * 256 + lane;
        atomicAdd(d, v0[0]); atomicAdd(d+64, v0[1]); atomicAdd(d+128, v0[2]); atomicAdd(d+192, v0[3]);
        d = lsum + ((rr.x >>  8 ) & 63u) * 256 + lane;
        atomicAdd(d, v1[0]); atomicAdd(d+64, v1[1]); atomicAdd(d+128, v1[2]); atomicAdd(d+192, v1[3]);
        d = lsum + ((rr.x >> 16 ) & 63u) * 256 + lane;
        atomicAdd(d, v2[0]); atomicAdd(d+64, v2[1]); atomicAdd(d+128, v2[2]); atomicAdd(d+192, v2[3]);
        d = lsum + ((rr.x >> 24 ) & 63u) * 256 + lane;
        atomicAdd(d, v3[0]); atomicAdd(d+64, v3[1]); atomicAdd(d+128, v3[2]); atomicAdd(d+192, v3[3]);
        d = lsum + ((rr.y       ) & 63u) * 256 + lane;
        atomicAdd(d, v4[0]); atomicAdd(d+64, v4[1]); atomicAdd(d+128, v4[2]); atomicAdd(d+192, v4[3]);
        d = lsum + ((rr.y >>  8 ) & 63u) * 256 + lane;
        atomicAdd(d, v5[0]); atomicAdd(d+64, v5[1]); atomicAdd(d+128, v5[2]); atomicAdd(d+192, v5[3]);
        d = lsum + ((rr.y >> 16 ) & 63u) * 256 + lane;
        atomicAdd(d, v6[0]); atomicAdd(d+64, v6[1]); atomicAdd(d+128, v6[2]); atomicAdd(d+192, v6[3]);
        d = lsum + ((rr.y >> 24 ) & 63u) * 256 + lane;
        atomicAdd(d, v7[0]); atomicAdd(d+64, v7[1]); atomicAdd(d+128, v7[2]); atomicAdd(d+192, v7[3]);
    }
    // tail: at most one partial 8-group at [row_hi & ~7, row_hi)
    if (row_hi > row_lo && (row_hi & 7)) {
        int tail0 = row_hi & ~7;
        if (tail0 < row_lo) tail0 = row_lo;
        if (w == (((tail0 - row_lo) >> 3) & 3)) {
            for (int row = tail0; row < row_hi; ++row) {
                unsigned r = rid[row] & 63u;
                const float* p = xq + (size_t)row * DIM;
                float* d = lsum + r * 256 + lane;
                atomicAdd(d, p[0]); atomicAdd(d+64, p[64]);
                atomicAdd(d+128, p[128]); atomicAdd(d+192, p[192]);
            }
        }
    }
    __syncthreads();
    for (int i = t; i < NREG * 256; i += 256) {
        int reg = i >> 8, cc = i & 255;
        unsafeAtomicAdd(&sums[(size_t)reg * DIM + q * 256 + cc], lsum[i]);
    }
}

// K4: gated attention scores, barrier-free: warp w owns attention row a.
__global__ __launch_bounds__(256) void k_scores(const float* __restrict__ sums,
                                                const unsigned* __restrict__ counts,
                                                const float* __restrict__ U_w,
                                                const float* __restrict__ U_b,
                                                const float* __restrict__ V_w,
                                                const float* __restrict__ V_b,
                                                const float* __restrict__ w_w,
                                                float* __restrict__ scores) {
    __shared__ float Us[4][DIM];
    __shared__ float Vs[4][DIM];
    int t = threadIdx.x, w = t >> 6, lane = t & 63;
    int a = blockIdx.x * 4 + w;
    const float4* U4 = (const float4*)(U_w + (size_t)a * DIM);
    const float4* V4 = (const float4*)(V_w + (size_t)a * DIM);
    #pragma unroll
    for (int s = 0; s < 4; ++s) {
        ((float4*)Us[w])[s * 64 + lane] = U4[s * 64 + lane];
        ((float4*)Vs[w])[s * 64 + lane] = V4[s * 64 + lane];
    }
    float ub = U_b[a], vb = V_b[a], ww = w_w[a];
    for (int reg = 0; reg < NREG; ++reg) {
        float inv = 1.0f / fmaxf((float)counts[reg], 1.0f);
        float du = 0.f, dv = 0.f;
        #pragma unroll
        for (int s = 0; s < 4; ++s) {
            float4 sv = ((const float4*)(sums + (size_t)reg * DIM))[s * 64 + lane];
            float4 u4 = ((const float4*)Us[w])[s * 64 + lane];
            float4 v4 = ((const float4*)Vs[w])[s * 64 + lane];
            float rx = sv.x * inv, ry = sv.y * inv, rz = sv.z * inv, rw = sv.w * inv;
            du = fmaf(u4.x, rx, fmaf(u4.y, ry, fmaf(u4.z, rz, fmaf(u4.w, rw, du))));
            dv = fmaf(v4.x, rx, fmaf(v4.y, ry, fmaf(v4.z, rz, fmaf(v4.w, rw, dv))));
        }
        for (int off = 32; off; off >>= 1) {
            du += __shfl_xor(du, off);
            dv += __shfl_xor(dv, off);
        }
        if (lane == 0) {
            float g = tanhf(du + ub) * (1.0f / (1.0f + expf(-(dv + vb))));
            unsafeAtomicAdd(&scores[reg], ww * g);
        }
    }
}

// K5: softmax + slide (redundant per block) + classifier rows. grid 64.
__global__ __launch_bounds__(256) void k_attn_cls(const float* __restrict__ scores,
                                                  const unsigned* __restrict__ counts,
                                                  const float* __restrict__ sums,
                                                  const float* __restrict__ c1_w,
                                                  const float* __restrict__ c1_b,
                                                  const float* __restrict__ c2_w,
                                                  float* __restrict__ out) {
    __shared__ float coef[NREG];
    __shared__ float slide[DIM];
    __shared__ float sp[4];
    int t = threadIdx.x;
    if (t < 64) {
        unsigned cnt = counts[t];
        float sc = (cnt > 0u) ? scores[t] : -INFINITY;
        float m = sc;
        for (int off = 32; off; off >>= 1) m = fmaxf(m, __shfl_xor(m, off));
        float e = expf(sc - m);
        float sum = e;
        for (int off = 32; off; off >>= 1) sum += __shfl_xor(sum, off);
        float a = e / sum;
        if (blockIdx.x == 0) out[1 + DIM + t] = a;
        coef[t] = a / fmaxf((float)cnt, 1.0f);
    }
    __syncthreads();
    f4 acc = (f4)(0.f);
    const f4* sums4 = (const f4*)sums;
    #pragma unroll 8
    for (int reg = 0; reg < NREG; ++reg)
        acc += coef[reg] * sums4[reg * 256 + t];
    ((f4*)slide)[t] = acc;
    if (blockIdx.x == 0) {
        float4 o = make_float4(acc.x, acc.y, acc.z, acc.w);
        ((float4*)(out + 1))[t] = o;
    }
    __syncthreads();
    int w = t >> 6, lane = t & 63;
    int j = blockIdx.x * 4 + w;
    const f4* cw4 = (const f4*)(c1_w + (size_t)j * DIM);
    const f4* sl4 = (const f4*)slide;
    float d = 0.f;
    #pragma unroll
    for (int jj = 0; jj < 4; ++jj) {
        f4 cc = cw4[lane + 64 * jj];
        f4 ss = sl4[lane + 64 * jj];
        d = fmaf(cc.x, ss.x, fmaf(cc.y, ss.y, fmaf(cc.z, ss.z, fmaf(cc.w, ss.w, d))));
    }
    for (int off = 32; off; off >>= 1) d += __shfl_xor(d, off);
    if (lane == 0) sp[w] = fmaxf(d + c1_b[j], 0.f) * c2_w[j];
    __syncthreads();
    if (t == 0) unsafeAtomicAdd(&out[0], sp[0] + sp[1] + sp[2] + sp[3]);
}

extern "C" void kernel_launch(void* const* d_in, const int* in_sizes, int n_in,
                              void* d_out, int out_size, void* d_ws, size_t ws_size,
                              hipStream_t stream) {
    const float*  x      = (const float*)d_in[0];
    const float2* coords = (const float2*)d_in[1];
    const float*  U_w    = (const float*)d_in[2];
    const float*  U_b    = (const float*)d_in[3];
    const float*  V_w    = (const float*)d_in[4];
    const float*  V_b    = (const float*)d_in[5];
    const float*  w_w    = (const float*)d_in[6];
    const float*  c1_w   = (const float*)d_in[7];
    const float*  c1_b   = (const float*)d_in[8];
    const float*  c2_w   = (const float*)d_in[9];
    const float*  c2_b   = (const float*)d_in[10];
    int N = in_sizes[0] / DIM;

    float* out = (float*)d_out;
    char* ws = (char*)d_ws;
    float*         sums    = (float*)(ws + SUMS_OFF);
    unsigned*      counts  = (unsigned*)(ws + CNT_OFF);
    float*         scores  = (float*)(ws + SCORE_OFF);
    float4*        partial = (float4*)(ws + PART_OFF);
    unsigned char* rid     = (unsigned char*)(ws + RID_OFF);

    int rpc = (((N + CHUNKS - 1) / CHUNKS) + 31) & ~31;   // rows/chunk, mult of 32

    hipLaunchKernelGGL(k_minmax_init, dim3(64), dim3(256), 0, stream,
                       coords, N, partial, sums, counts, scores, out, c2_b);
    hipLaunchKernelGGL(k_rid, dim3((N + 255) / 256), dim3(256), 0, stream,
                       coords, N, partial, rid, counts);
    hipLaunchKernelGGL(k_segsum, dim3(CHUNKS * 4), dim3(256), 0, stream,
                       x, rid, N, rpc, sums);
    hipLaunchKernelGGL(k_scores, dim3(ADIM / 4), dim3(256), 0, stream,
                       sums, counts, U_w, U_b, V_w, V_b, w_w, scores);
    hipLaunchKernelGGL(k_attn_cls, dim3(64), dim3(256), 0, stream,
                       scores, counts, sums, c1_w, c1_b, c2_w, out);
}